// Round 14
// baseline (659.648 us; speedup 1.0000x reference)
//
#include <hip/hip_runtime.h>
#include <stdint.h>

// Problem constants (from reference)
#define NN      5000
#define NB      8
#define TSTEPS  256
#define NDELAY  15
#define NW      157          // uint32 words covering 5000 presyn bits
#define NIPAD   5120         // padded neuron dim (columns of maskT2)
#define RW      160          // ring row stride in words (640 B, 16B-aligned)
#define IPB     512          // 256 neurons x 2 half-rows
#define NSL     20           // 256-neuron slices per batch
#define NBLK    (NB*NSL)     // 160 blocks -> 1 per CU, 8 waves -> 2/SIMD
#define CH      4            // chunk length (64 chunks)
#define NCHUNK  (TSTEPS/CH)  // 64
#define BARSTRIDE 16         // ints between chunk counters (64B apart)
#define RING_DEPTH 256       // WRITE-ONCE ring: slot = step + 15 (no reuse)

// Workspace layout (bytes)
#define MASK_BYTES (160*NIPAD*4)             // 3,276,800 (rows 157..159 zero)
#define BAR_OFF    MASK_BYTES
#define BAR_BYTES  (64*BARSTRIDE*4)          // 4,096
#define RING_OFF   (BAR_OFF + BAR_BYTES)
#define RING_BYTES (RING_DEPTH*NB*RW*4)      // 1,310,720
#define ZERO_BYTES (RING_OFF + RING_BYTES)   // ~4.59 MB total

// ---------------------------------------------------------------------------
// Kernel 1: bit-pack connectivity, word-major-transposed:
//   maskT2[w*NIPAD + i] bit (j&31), w=j>>5, set iff W[i,j] != 0.
// ---------------------------------------------------------------------------
__global__ void _Brunel_build_mask(const float* __restrict__ W,
                                   uint32_t* __restrict__ maskT2)
{
    int j = blockIdx.x * blockDim.x + threadIdx.x;   // presyn 0..5119
    int i = blockIdx.y;                              // postsyn row 0..4999
    int lane = threadIdx.x & 63;
    bool nz = false;
    if (j < NN) nz = (W[(size_t)i * NN + j] != 0.0f);
    unsigned long long m = __ballot(nz);
    if ((lane & 31) == 0 && j < NN) {
        uint32_t wd = (lane == 0) ? (uint32_t)m : (uint32_t)(m >> 32);
        maskT2[(size_t)(j >> 5) * NIPAD + i] = wd;
    }
}

// ---------------------------------------------------------------------------
// Kernel 2: persistent SNN sim, half-row K-split INSIDE the wave.
//  Wave = 32 neurons x 2 halves (h = lane>>5). h0 owns mask words 0..75
//  (+76..79 read-but-killed), h1 owns 76..155 + word 156. Identical
//  instruction shape both halves (no divergence): E/I boundary handled by
//  per-lane shift shA = h*16 into packed acc = cE | cI<<16 (fields can't
//  carry: cE<=4000, cI<=1120). Halves combined with __shfl_xor(.,32).
//  512-thr blocks -> 8 waves -> 2 waves/SIMD: hides the uniform-load and
//  LDS latency that capped R8/R11/R13 at ~460-520us with 1 wave/SIMD.
//  Spikes: R13's wave-(half-)uniform CACHED loads from the write-once ring
//  (slot = step+15, never rewritten within a launch -> caching safe).
//  Mask: LDS rows stride 156 words -- verified conflict-free for the
//  2-half b128 pattern (8 dwords/bank, balanced).
//  Sync: per-chunk barc counters, sc0sc1 ring writes, vmcnt(0)+barrier
//  arrive, gate poll barc[m-3] -- proven in R8..R13.
// ---------------------------------------------------------------------------
__global__ void __launch_bounds__(IPB, 2) _Brunel_persist(
    const float* __restrict__ ext,
    const uint32_t* __restrict__ maskT2,
    uint32_t* __restrict__ ring,
    int* __restrict__ barc,
    float* __restrict__ out_spk,
    float* __restrict__ out_vs)
{
    const int tx   = threadIdx.x;
    const int wv   = tx >> 6;            // wave 0..7
    const int lane = tx & 63;
    const int h    = lane >> 5;          // half-row 0/1
    const int ln32 = lane & 31;
    const int nl   = wv * 32 + ln32;     // block-local neuron 0..255
    const int bb   = blockIdx.x;
    const int b    = bb / NSL;
    const int sl   = bb % NSL;
    const int i    = sl * 256 + nl;
    const bool act = (i < NN);

    __shared__ __align__(16) uint32_t s_mask[256][156];   // 159,744 B
    __shared__ uint32_t s_mask156[256];                   //   1,024 B

    // ---- one-time: mask rows -> LDS (each thread loads its half-row) ----
    for (int w2 = 0; w2 < 79; ++w2) {
        int w = 78 * h + w2;             // h0: 0..77(78 skip), h1: 78..156
        if (w < NW) {
            uint32_t mv = maskT2[(size_t)w * NIPAD + i];  // pad cols are 0
            if (w < 156) s_mask[nl][w] = mv; else s_mask156[nl] = mv;
        }
    }
    __syncthreads();

    float v = 0.0f;

    // per-lane constants for the half-split inner loop
    const int      qoff  = h ? 19 : 0;          // uint4 base index (words 76)
    const uint32_t shA   = h ? 16u : 0u;        // inh shift for 4c+j >= 49
    const uint32_t kill  = h ? 0xFFFFFFFFu : 0u;     // c==19 valid only on h1
    const uint32_t sel156= h ? 0xFFFFFFFFu : 0u;     // word 156 counted on h1
    const uint32_t* __restrict__ mrow = s_mask[nl];

    for (int t0 = 0, m = 0; t0 < TSTEPS; t0 += CH, ++m) {
        // ---- prefetch external inputs for this chunk ----
        float x0 = 0.f, x1 = 0.f, x2 = 0.f, x3 = 0.f;
        if (act) {
            const float* e0 = ext + ((size_t)t0 * NB + b) * NN + i;
            const size_t st = (size_t)NB * NN;
            x0 = e0[0]; x1 = e0[st]; x2 = e0[2 * st]; x3 = e0[3 * st];
        }

        // ---- gate: all blocks finished chunk m-3 (writers of our slots) ----
        if (m >= 3) {
            if (tx == 0) {
                const int* c3 = barc + (size_t)(m - 3) * BARSTRIDE;
                while (__hip_atomic_load(c3, __ATOMIC_RELAXED,
                                         __HIP_MEMORY_SCOPE_AGENT) < NBLK)
                    __builtin_amdgcn_s_sleep(2);
            }
            __syncthreads();     // no reads may pass the gate
        }

        // ---- spike rows: slots t0..t0+3 of the write-once ring ----
        const uint4* __restrict__ s0 =
            (const uint4*)(ring + ((size_t)(t0 + 0) * NB + b) * RW);
        const uint4* __restrict__ s1 =
            (const uint4*)(ring + ((size_t)(t0 + 1) * NB + b) * RW);
        const uint4* __restrict__ s2 =
            (const uint4*)(ring + ((size_t)(t0 + 2) * NB + b) * RW);
        const uint4* __restrict__ s3 =
            (const uint4*)(ring + ((size_t)(t0 + 3) * NB + b) * RW);

        // ---- packed synapse counts: acc = cE | cI<<16 over own half ----
        uint32_t acc0 = 0, acc1 = 0, acc2 = 0, acc3 = 0;

#define HALF_WORD(c, j, MW, A0, A1, A2, A3)                                   \
        if (4 * (c) + (j) < 49) {            /* both halves excitatory */     \
            acc0 += (uint32_t)__popc((MW) & (A0));                            \
            acc1 += (uint32_t)__popc((MW) & (A1));                            \
            acc2 += (uint32_t)__popc((MW) & (A2));                            \
            acc3 += (uint32_t)__popc((MW) & (A3));                            \
        } else {                             /* h0: exc(sh0); h1: inh(<<16) */\
            acc0 += (uint32_t)__popc((MW) & (A0)) << shA;                     \
            acc1 += (uint32_t)__popc((MW) & (A1)) << shA;                     \
            acc2 += (uint32_t)__popc((MW) & (A2)) << shA;                     \
            acc3 += (uint32_t)__popc((MW) & (A3)) << shA;                     \
        }

#pragma unroll 4
        for (int c = 0; c < 20; ++c) {
            uint4 m4 = *(const uint4*)(mrow + 4 * (qoff + c));
            if (c == 19) { m4.x &= kill; m4.y &= kill; m4.z &= kill; m4.w &= kill; }
            uint4 a0 = s0[qoff + c], a1 = s1[qoff + c],
                  a2 = s2[qoff + c], a3 = s3[qoff + c];
            HALF_WORD(c, 0, m4.x, a0.x, a1.x, a2.x, a3.x)
            HALF_WORD(c, 1, m4.y, a0.y, a1.y, a2.y, a3.y)
            HALF_WORD(c, 2, m4.z, a0.z, a1.z, a2.z, a3.z)
            HALF_WORD(c, 3, m4.w, a0.w, a1.w, a2.w, a3.w)
        }
#undef HALF_WORD
        {   // word 156 (inhibitory, h1 only via sel156)
            uint32_t mL = s_mask156[nl] & sel156;
            acc0 += (uint32_t)__popc(mL & ((const uint32_t*)s0)[156]) << 16;
            acc1 += (uint32_t)__popc(mL & ((const uint32_t*)s1)[156]) << 16;
            acc2 += (uint32_t)__popc(mL & ((const uint32_t*)s2)[156]) << 16;
            acc3 += (uint32_t)__popc(mL & ((const uint32_t*)s3)[156]) << 16;
        }

        // ---- combine halves (lane ^ 32): totals land in both halves ----
        acc0 += (uint32_t)__shfl_xor((int)acc0, 32);
        acc1 += (uint32_t)__shfl_xor((int)acc1, 32);
        acc2 += (uint32_t)__shfl_xor((int)acc2, 32);
        acc3 += (uint32_t)__shfl_xor((int)acc3, 32);

        // ---- 4 sequential neuron updates + write-once ring publish ----
#define BRUNEL_STEP(kk, ACC, xk)                                              \
        {                                                                     \
            const int t = t0 + kk;                                            \
            int cE = (int)((ACC) & 0xFFFFu);                                  \
            int cI = (int)((ACC) >> 16);                                      \
            float cur = 0.1f * (float)cE - 0.5f * (float)cI;                  \
            v = v * 0.95f + (cur + xk);                                       \
            bool s = act && (v >= 1.0f);                                      \
            float vout = s ? 0.0f : v;                                        \
            if (act && h == 0) {                                              \
                size_t o = ((size_t)t * NB + b) * NN + i;                     \
                out_spk[o] = s ? 1.0f : 0.0f;                                 \
                out_vs[o]  = vout;                                            \
            }                                                                 \
            v = vout;                                                         \
            unsigned long long bm = __ballot(s);                              \
            if (lane == 0 && t <= TSTEPS - 1 - NDELAY) {                      \
                __hip_atomic_store(                                           \
                    &ring[((size_t)(t + NDELAY) * NB + b) * RW + sl * 8 + wv],\
                    (uint32_t)bm, __ATOMIC_RELAXED, __HIP_MEMORY_SCOPE_AGENT);\
            }                                                                 \
        }
        BRUNEL_STEP(0, acc0, x0)
        BRUNEL_STEP(1, acc1, x1)
        BRUNEL_STEP(2, acc2, x2)
        BRUNEL_STEP(3, acc3, x3)
#undef BRUNEL_STEP

        // ---- arrive: per-wave store drain, block barrier, relaxed add ----
        asm volatile("s_waitcnt vmcnt(0)" ::: "memory");  // ring stores at LLC
        __syncthreads();
        if (tx == 0)
            __hip_atomic_fetch_add(barc + (size_t)m * BARSTRIDE, 1,
                                   __ATOMIC_RELAXED, __HIP_MEMORY_SCOPE_AGENT);
    }
}

// ---------------------------------------------------------------------------
extern "C" void kernel_launch(void* const* d_in, const int* in_sizes, int n_in,
                              void* d_out, int out_size, void* d_ws, size_t ws_size,
                              hipStream_t stream)
{
    const float* ext = (const float*)d_in[0];   // [T,B,N] fp32
    const float* W   = (const float*)d_in[1];   // [N,N]   fp32

    float* out_spk = (float*)d_out;                          // [T,B,N]
    float* out_vs  = out_spk + (size_t)TSTEPS * NB * NN;     // [T,B,N]

    uint8_t*  ws   = (uint8_t*)d_ws;
    uint32_t* mask = (uint32_t*)(ws);
    int*      barc = (int*)(ws + BAR_OFF);
    uint32_t* ring = (uint32_t*)(ws + RING_OFF);

    // zero mask (incl. pad rows 157..159) + counters + whole write-once ring
    // (slots 0..14 MUST be zero: they serve ts<0 reads)
    hipMemsetAsync(ws, 0, ZERO_BYTES, stream);

    dim3 gmask(NIPAD / 256, NN);   // (20, 5000), 256 threads
    _Brunel_build_mask<<<gmask, 256, 0, stream>>>(W, mask);

    _Brunel_persist<<<NBLK, IPB, 0, stream>>>(ext, mask, ring, barc,
                                              out_spk, out_vs);
}

// Round 15
// 610.167 us; speedup vs baseline: 1.0811x; 1.0811x over previous
//
#include <hip/hip_runtime.h>
#include <stdint.h>

// Problem constants (from reference)
#define NN      5000
#define NB      8
#define TSTEPS  256
#define NDELAY  15
#define NW      157          // uint32 words covering 5000 presyn bits
#define NIPAD   5120         // padded neuron dim (columns of maskT2)
#define RW      160          // ring row stride in words (640 B, 16B-aligned)
#define IPB     256          // threads per block
#define BPB     20           // blocks per batch
#define NBLK    (NB*BPB)     // 160 blocks -> 1 per CU, co-resident
#define CH      4            // chunk length (64 chunks)
#define NCHUNK  (TSTEPS/CH)  // 64
#define BARSTRIDE 16         // ints between chunk counters (64B apart)
#define RING_DEPTH 256       // WRITE-ONCE ring: slot = step + 15 (no reuse)

// Workspace layout (bytes)
#define MASK_BYTES (NW*NIPAD*4)              // 3,215,360
#define BAR_OFF    MASK_BYTES
#define BAR_BYTES  (64*BARSTRIDE*4)          // 4,096
#define RING_OFF   (BAR_OFF + BAR_BYTES)     // 16B-aligned
#define RING_BYTES (RING_DEPTH*NB*RW*4)      // 1,310,720
#define ZERO_BYTES (RING_OFF + RING_BYTES)   // ~4.53 MB total

typedef uint32_t u32x16 __attribute__((ext_vector_type(16)));

// ---------------------------------------------------------------------------
// Kernel 1: bit-pack connectivity, word-major-transposed:
//   maskT2[w*NIPAD + i] bit (j&31), w=j>>5, set iff W[i,j] != 0.
// ---------------------------------------------------------------------------
__global__ void _Brunel_build_mask(const float* __restrict__ W,
                                   uint32_t* __restrict__ maskT2)
{
    int j = blockIdx.x * blockDim.x + threadIdx.x;   // presyn 0..5119
    int i = blockIdx.y;                              // postsyn row 0..4999
    int lane = threadIdx.x & 63;
    bool nz = false;
    if (j < NN) nz = (W[(size_t)i * NN + j] != 0.0f);
    unsigned long long m = __ballot(nz);
    if ((lane & 31) == 0 && j < NN) {
        uint32_t wd = (lane == 0) ? (uint32_t)m : (uint32_t)(m >> 32);
        maskT2[(size_t)(j >> 5) * NIPAD + i] = wd;
    }
}

// ---------------------------------------------------------------------------
// Kernel 2: persistent SNN sim.
//  Round-15 change vs R13: spike words fetched through the SCALAR pipe --
//  s_load_dwordx16 (64B/load, 40 loads/chunk) into SGPRs. v_and v,s,v
//  consumes SGPR operands directly: VALU stays at the 2-op/word/step floor
//  (and + fused v_bcnt), zero broadcast ops, zero spike VMEM, zero spike
//  LDS. Coherence: identical write-once-ring argument as R13 (slot=step+15,
//  line never rewritten within a launch; readers gated after writers'
//  sc0sc1 stores reach LLC; deterministic values make cross-launch stale
//  lines self-healing). R13 passing validates this design for cached reads.
//  Mask stays in LDS (per-lane ds_read_b128, ~37/wave/chunk, conflict-free).
//  Sync: per-chunk barc, vmcnt(0)+barrier arrive, gate poll barc[m-3] --
//  unchanged from R8..R13.
// ---------------------------------------------------------------------------
__global__ void __launch_bounds__(IPB, 1) _Brunel_persist(
    const float* __restrict__ ext,
    const uint32_t* __restrict__ maskT2,
    uint32_t* __restrict__ ring,
    int* __restrict__ barc,
    float* __restrict__ out_spk,
    float* __restrict__ out_vs)
{
    const int tx   = threadIdx.x;
    const int bb   = blockIdx.x;
    const int b    = bb / BPB;
    const int i    = (bb % BPB) * IPB + tx;
    const bool act = (i < NN);
    const int lane = tx & 63;

    __shared__ __align__(16) uint32_t s_mask[IPB][156];   // 159,744 B
    __shared__ uint32_t s_mask156[IPB];                   //   1,024 B

    // ---- one-time: mask row -> LDS (own row only; coalesced over tx) ----
    for (int w = 0; w < NW; ++w) {
        uint32_t mv = maskT2[(size_t)w * NIPAD + i];      // pad cols are 0
        if (w < 156) s_mask[tx][w] = mv; else s_mask156[tx] = mv;
    }
    __syncthreads();

    const uint64_t ring64 = (uint64_t)(uintptr_t)ring;
    float v = 0.0f;

    for (int t0 = 0, m = 0; t0 < TSTEPS; t0 += CH, ++m) {
        // ---- prefetch external inputs for this chunk ----
        float x0 = 0.f, x1 = 0.f, x2 = 0.f, x3 = 0.f;
        if (act) {
            const float* e0 = ext + ((size_t)t0 * NB + b) * NN + i;
            const size_t st = (size_t)NB * NN;
            x0 = e0[0]; x1 = e0[st]; x2 = e0[2 * st]; x3 = e0[3 * st];
        }

        // ---- gate: all blocks finished chunk m-3 (writers of our slots) ----
        if (m >= 3) {
            if (tx == 0) {
                const int* c3 = barc + (size_t)(m - 3) * BARSTRIDE;
                while (__hip_atomic_load(c3, __ATOMIC_RELAXED,
                                         __HIP_MEMORY_SCOPE_AGENT) < NBLK)
                    __builtin_amdgcn_s_sleep(2);
            }
            __syncthreads();     // no reads may pass the gate
        }

        // ---- per-step byte offsets into the write-once ring ----
        const uint32_t sb0 = (uint32_t)((((t0 + 0) * NB + b) * RW) * 4);
        const uint32_t sb1 = (uint32_t)((((t0 + 1) * NB + b) * RW) * 4);
        const uint32_t sb2 = (uint32_t)((((t0 + 2) * NB + b) * RW) * 4);
        const uint32_t sb3 = (uint32_t)((((t0 + 3) * NB + b) * RW) * 4);

        int cE0 = 0, cE1 = 0, cE2 = 0, cE3 = 0;
        int cI0 = 0, cI1 = 0, cI2 = 0, cI3 = 0;
        const uint32_t* __restrict__ mrow = s_mask[tx];

#define SMEM_LD4(D0, D1, D2, D3, OFF)                                         \
        asm volatile("s_load_dwordx16 %0, %4, %5\n\t"                         \
                     "s_load_dwordx16 %1, %4, %6\n\t"                         \
                     "s_load_dwordx16 %2, %4, %7\n\t"                         \
                     "s_load_dwordx16 %3, %4, %8\n\t"                         \
                     "s_waitcnt lgkmcnt(0)"                                   \
                     : "=s"(D0), "=s"(D1), "=s"(D2), "=s"(D3)                 \
                     : "s"(ring64), "s"(sb0 + (OFF)), "s"(sb1 + (OFF)),       \
                       "s"(sb2 + (OFF)), "s"(sb3 + (OFF))                     \
                     : "memory");

#define WRD(G, J, MW)                                                         \
        if ((16 * (G) + (J)) < 125) {                                         \
            cE0 += __popc((MW) & d0[J]); cE1 += __popc((MW) & d1[J]);         \
            cE2 += __popc((MW) & d2[J]); cE3 += __popc((MW) & d3[J]);         \
        } else {                                                              \
            cI0 += __popc((MW) & d0[J]); cI1 += __popc((MW) & d1[J]);         \
            cI2 += __popc((MW) & d2[J]); cI3 += __popc((MW) & d3[J]);         \
        }

#pragma unroll
        for (int g = 0; g < 9; ++g) {       // words 16g .. 16g+15 (0..143)
            u32x16 d0, d1, d2, d3;
            SMEM_LD4(d0, d1, d2, d3, 64u * g)
            uint4 mA = *(const uint4*)(mrow + 16 * g + 0);
            uint4 mB = *(const uint4*)(mrow + 16 * g + 4);
            uint4 mC = *(const uint4*)(mrow + 16 * g + 8);
            uint4 mD = *(const uint4*)(mrow + 16 * g + 12);
            WRD(g,  0, mA.x) WRD(g,  1, mA.y) WRD(g,  2, mA.z) WRD(g,  3, mA.w)
            WRD(g,  4, mB.x) WRD(g,  5, mB.y) WRD(g,  6, mB.z) WRD(g,  7, mB.w)
            WRD(g,  8, mC.x) WRD(g,  9, mC.y) WRD(g, 10, mC.z) WRD(g, 11, mC.w)
            WRD(g, 12, mD.x) WRD(g, 13, mD.y) WRD(g, 14, mD.z) WRD(g, 15, mD.w)
        }
        {   // group 9: words 144..155 (inh) + word 156 (inh); 157..159 pad
            u32x16 d0, d1, d2, d3;
            SMEM_LD4(d0, d1, d2, d3, 576u)
            uint4 mA = *(const uint4*)(mrow + 144);
            uint4 mB = *(const uint4*)(mrow + 148);
            uint4 mC = *(const uint4*)(mrow + 152);
            cI0 += __popc(mA.x & d0[0]) + __popc(mA.y & d0[1])
                 + __popc(mA.z & d0[2]) + __popc(mA.w & d0[3])
                 + __popc(mB.x & d0[4]) + __popc(mB.y & d0[5])
                 + __popc(mB.z & d0[6]) + __popc(mB.w & d0[7])
                 + __popc(mC.x & d0[8]) + __popc(mC.y & d0[9])
                 + __popc(mC.z & d0[10]) + __popc(mC.w & d0[11]);
            cI1 += __popc(mA.x & d1[0]) + __popc(mA.y & d1[1])
                 + __popc(mA.z & d1[2]) + __popc(mA.w & d1[3])
                 + __popc(mB.x & d1[4]) + __popc(mB.y & d1[5])
                 + __popc(mB.z & d1[6]) + __popc(mB.w & d1[7])
                 + __popc(mC.x & d1[8]) + __popc(mC.y & d1[9])
                 + __popc(mC.z & d1[10]) + __popc(mC.w & d1[11]);
            cI2 += __popc(mA.x & d2[0]) + __popc(mA.y & d2[1])
                 + __popc(mA.z & d2[2]) + __popc(mA.w & d2[3])
                 + __popc(mB.x & d2[4]) + __popc(mB.y & d2[5])
                 + __popc(mB.z & d2[6]) + __popc(mB.w & d2[7])
                 + __popc(mC.x & d2[8]) + __popc(mC.y & d2[9])
                 + __popc(mC.z & d2[10]) + __popc(mC.w & d2[11]);
            cI3 += __popc(mA.x & d3[0]) + __popc(mA.y & d3[1])
                 + __popc(mA.z & d3[2]) + __popc(mA.w & d3[3])
                 + __popc(mB.x & d3[4]) + __popc(mB.y & d3[5])
                 + __popc(mB.z & d3[6]) + __popc(mB.w & d3[7])
                 + __popc(mC.x & d3[8]) + __popc(mC.y & d3[9])
                 + __popc(mC.z & d3[10]) + __popc(mC.w & d3[11]);
            uint32_t mL = s_mask156[tx];    // word 156 = element 12
            cI0 += __popc(mL & d0[12]);
            cI1 += __popc(mL & d1[12]);
            cI2 += __popc(mL & d2[12]);
            cI3 += __popc(mL & d3[12]);
        }
#undef WRD
#undef SMEM_LD4

        // ---- 4 sequential neuron updates + write-once ring publish ----
#define BRUNEL_STEP(kk, xk)                                                   \
        {                                                                     \
            const int t = t0 + kk;                                            \
            float cur = 0.1f * (float)cE##kk - 0.5f * (float)cI##kk;          \
            v = v * 0.95f + (cur + xk);                                       \
            bool s = act && (v >= 1.0f);                                      \
            float sflag = s ? 1.0f : 0.0f;                                    \
            float vout  = s ? 0.0f : v;                                       \
            if (act) {                                                        \
                size_t o = ((size_t)t * NB + b) * NN + i;                     \
                out_spk[o] = sflag;                                           \
                out_vs[o]  = vout;                                            \
            }                                                                 \
            v = vout;                                                         \
            unsigned long long bm = __ballot(s);                              \
            if ((lane & 31) == 0 && act && t <= TSTEPS - 1 - NDELAY) {        \
                uint32_t wd = (lane == 0) ? (uint32_t)bm : (uint32_t)(bm >> 32); \
                __hip_atomic_store(                                           \
                    &ring[((size_t)(t + NDELAY) * NB + b) * RW + (i >> 5)],   \
                    wd, __ATOMIC_RELAXED, __HIP_MEMORY_SCOPE_AGENT);          \
            }                                                                 \
        }
        BRUNEL_STEP(0, x0)
        BRUNEL_STEP(1, x1)
        BRUNEL_STEP(2, x2)
        BRUNEL_STEP(3, x3)
#undef BRUNEL_STEP

        // ---- arrive: per-wave store drain, block barrier, relaxed add ----
        asm volatile("s_waitcnt vmcnt(0)" ::: "memory");  // ring stores at LLC
        __syncthreads();
        if (tx == 0)
            __hip_atomic_fetch_add(barc + (size_t)m * BARSTRIDE, 1,
                                   __ATOMIC_RELAXED, __HIP_MEMORY_SCOPE_AGENT);
    }
}

// ---------------------------------------------------------------------------
extern "C" void kernel_launch(void* const* d_in, const int* in_sizes, int n_in,
                              void* d_out, int out_size, void* d_ws, size_t ws_size,
                              hipStream_t stream)
{
    const float* ext = (const float*)d_in[0];   // [T,B,N] fp32
    const float* W   = (const float*)d_in[1];   // [N,N]   fp32

    float* out_spk = (float*)d_out;                          // [T,B,N]
    float* out_vs  = out_spk + (size_t)TSTEPS * NB * NN;     // [T,B,N]

    uint8_t*  ws   = (uint8_t*)d_ws;
    uint32_t* mask = (uint32_t*)(ws);
    int*      barc = (int*)(ws + BAR_OFF);
    uint32_t* ring = (uint32_t*)(ws + RING_OFF);

    // zero mask (pad cols) + per-chunk counters + whole write-once ring
    // (slots 0..14 MUST be zero: they serve ts<0 reads)
    hipMemsetAsync(ws, 0, ZERO_BYTES, stream);

    dim3 gmask(NIPAD / IPB, NN);   // (20, 5000)
    _Brunel_build_mask<<<gmask, IPB, 0, stream>>>(W, mask);

    _Brunel_persist<<<NBLK, IPB, 0, stream>>>(ext, mask, ring, barc,
                                              out_spk, out_vs);
}